// Round 1
// baseline (724.338 us; speedup 1.0000x reference)
//
#include <hip/hip_runtime.h>
#include <stdint.h>

namespace {

constexpr int Bb = 8, Nn = 128, Tt = 8, Ll = 6, Dd = 256, Pp = 1024; // Pp = Nn*Tt
constexpr float INV_TEMP = 14.285714285714286f;  // 1/0.07
constexpr float M0f = 16.0f;                     // fixed LSE shift, > max |z| = 14.2857

// ---------------- JAX threefry2x32 (key = (0, 42)), bit-exact ----------------
__device__ __forceinline__ uint32_t rotl32(uint32_t x, int n) {
  return (x << n) | (x >> (32 - n));
}
__device__ __forceinline__ void tf_round(uint32_t& x0, uint32_t& x1, int r) {
  x0 += x1; x1 = rotl32(x1, r); x1 ^= x0;
}
__device__ void threefry2x32(uint32_t x0, uint32_t x1, uint32_t& o0, uint32_t& o1) {
  const uint32_t k0 = 0u, k1 = 42u;
  const uint32_t k2 = k0 ^ k1 ^ 0x1BD11BDAu;
  x0 += k0; x1 += k1;
  tf_round(x0,x1,13); tf_round(x0,x1,15); tf_round(x0,x1,26); tf_round(x0,x1,6);
  x0 += k1; x1 += k2 + 1u;
  tf_round(x0,x1,17); tf_round(x0,x1,29); tf_round(x0,x1,16); tf_round(x0,x1,24);
  x0 += k2; x1 += k0 + 2u;
  tf_round(x0,x1,13); tf_round(x0,x1,15); tf_round(x0,x1,26); tf_round(x0,x1,6);
  x0 += k0; x1 += k1 + 3u;
  tf_round(x0,x1,17); tf_round(x0,x1,29); tf_round(x0,x1,16); tf_round(x0,x1,24);
  x0 += k1; x1 += k2 + 4u;
  tf_round(x0,x1,13); tf_round(x0,x1,15); tf_round(x0,x1,26); tf_round(x0,x1,6);
  x0 += k2; x1 += k0 + 5u;
  o0 = x0; o1 = x1;
}
// u[idx] for jax.random.uniform(key(42), (B,L,P)) flat index idx in [0, B*L*P)
__device__ float jax_u01(uint32_t idx) {
  const uint32_t HALF = (uint32_t)(Bb * Ll * Pp / 2); // 24576 (even size)
  uint32_t o0, o1, bits;
  if (idx < HALF) { threefry2x32(idx, idx + HALF, o0, o1); bits = o0; }
  else            { threefry2x32(idx - HALF, idx, o0, o1); bits = o1; }
  return __uint_as_float((bits >> 9) | 0x3f800000u) - 1.0f;
}

// ---------------- kernel 1: per-batch K and gate ----------------
__global__ void batch_stats_k(const int* __restrict__ thing, int* __restrict__ Kv,
                              int* __restrict__ gatev) {
  const int b = blockIdx.x, t = threadIdx.x;
  __shared__ int sK[256], sG[256];
  int k = 0;
  for (int p = t; p < Pp; p += 256) k += (thing[b * Pp + p] != 0);
  int g = 0;
  for (int n = t; n < Nn; n += 256) {
    int any = 0;
    for (int tt = 0; tt < Tt; ++tt) any |= (thing[(b * Nn + n) * Tt + tt] != 0);
    g += any;
  }
  sK[t] = k; sG[t] = g;
  __syncthreads();
  for (int s = 128; s; s >>= 1) {
    if (t < s) { sK[t] += sK[t + s]; sG[t] += sG[t + s]; }
    __syncthreads();
  }
  if (t == 0) { Kv[b] = sK[0]; gatev[b] = (sG[0] >= 2) ? 1 : 0; }
}

// ---------------- kernel 2: per-row stats + threefry positive selection ----------------
__global__ void row_stats_k(const int* __restrict__ thing, const int* __restrict__ label,
                            int* __restrict__ qpos, int* __restrict__ negc,
                            int* __restrict__ qidx) {
  const int gid = blockIdx.x * blockDim.x + threadIdx.x;
  if (gid >= Bb * Pp) return;
  const int b = gid >> 10, p = gid & (Pp - 1);
  const int* lab = label + b * Pp;
  const int* th  = thing + b * Pp;
  const int myLab = lab[p];
  const int myValid = (th[p] != 0);
  int pc = 0, nc = 0, last = -1;
  for (int q = 0; q < Pp; ++q) {
    const int vq = (th[q] != 0);
    const bool same = (lab[q] == myLab);
    if (myValid && vq) {
      if (same) { if (q != p) ++pc; }
      else      { ++nc; last = q; }
    }
  }
  negc[gid] = nc;
  qidx[gid] = (last < 0) ? 0 : last;

  int r[Ll];
  for (int l = 0; l < Ll; ++l) {
    if (pc > 0) {
      const float u = jax_u01((uint32_t)((b * Ll + l) * Pp + p));
      int rr = (int)floorf(u * (float)pc);
      r[l] = min(rr, pc - 1);
    } else r[l] = -1;
  }
  int qsel[Ll];
  for (int l = 0; l < Ll; ++l) qsel[l] = p;   // diag fallback when pc==0
  if (pc > 0) {
    int rank = 0;
    for (int q = 0; q < Pp; ++q) {
      if (q != p && th[q] != 0 && lab[q] == myLab) {
        #pragma unroll
        for (int l = 0; l < Ll; ++l) if (rank == r[l]) qsel[l] = q;
        ++rank;
      }
    }
  }
  for (int l = 0; l < Ll; ++l) qpos[(b * Ll + l) * Pp + p] = qsel[l];
}

// ---------------- kernel 3: inverse L2 norms, one wave per (b,p,l) vector ----------------
__global__ void norms_k(const float* __restrict__ meta, float* __restrict__ invn) {
  const int wid = (blockIdx.x * blockDim.x + threadIdx.x) >> 6;  // = (b*P+p)*L+l
  const int lane = threadIdx.x & 63;
  if (wid >= Bb * Pp * Ll) return;
  const float* src = meta + (size_t)wid * Dd;
  float4 v = *(const float4*)(src + lane * 4);
  float ss = v.x * v.x + v.y * v.y + v.z * v.z + v.w * v.w;
  #pragma unroll
  for (int m = 32; m; m >>= 1) ss += __shfl_xor(ss, m, 64);
  if (lane == 0) invn[wid] = 1.0f / fmaxf(sqrtf(ss), 1e-12f);
}

// ---------------- kernel 4: fused tiled GEMM + masked LSE epilogue ----------------
// tile: 64 rows (p) x 128 cols (q), TK=16; 256 threads; thread = 4x8 register tile
constexpr int TM = 64, TN = 128, TK = 16;

__global__ __launch_bounds__(256)
void main_loss_k(const float* __restrict__ meta, const float* __restrict__ invn,
                 const int* __restrict__ thing, const int* __restrict__ label,
                 const int* __restrict__ qpos, const int* __restrict__ negc,
                 const int* __restrict__ qidx, const int* __restrict__ Kv,
                 const int* __restrict__ gatev, float* __restrict__ out) {
  __shared__ float A_lds[TK][TM + 4];
  __shared__ float B_lds[TK][TN + 4];
  __shared__ int   qlab[TN], qval[TN];
  __shared__ float qinv[TN];
  __shared__ int   labp_s[TM], qpos_s[TM], qidx_s[TM], valp_s[TM];
  __shared__ float invA[TM], rowsum[TM], zp_s[TM], zl_s[TM];

  const int t = threadIdx.x;
  const int b = blockIdx.z, l = blockIdx.y;
  const int p0 = blockIdx.x * TM;

  if (t < TM) {
    const int p = p0 + t;
    labp_s[t] = label[b * Pp + p];
    valp_s[t] = thing[b * Pp + p];
    qpos_s[t] = qpos[(b * Ll + l) * Pp + p];
    qidx_s[t] = qidx[b * Pp + p];
    invA[t]   = invn[((size_t)(b * Pp + p)) * Ll + l];
    rowsum[t] = 0.f; zp_s[t] = 0.f; zl_s[t] = 0.f;
  }
  __syncthreads();

  const int i = t >> 4;   // 0..15 -> rows 4i..4i+3
  const int j = t & 15;   // 0..15 -> cols 8j..8j+7
  int labr[4], qpr[4], qir[4];
  #pragma unroll
  for (int m = 0; m < 4; ++m) {
    labr[m] = labp_s[4 * i + m]; qpr[m] = qpos_s[4 * i + m]; qir[m] = qidx_s[4 * i + m];
  }
  float partial[4] = {0.f, 0.f, 0.f, 0.f};

  const int arow = t >> 2;   // 0..63
  const int aseg = t & 3;    // 0..3 (k sub-segment, 4 floats each)

  for (int q0 = 0; q0 < Pp; q0 += TN) {
    __syncthreads();  // previous epilogue done reading qlab/qval
    if (t < TN) {
      qlab[t] = label[b * Pp + q0 + t];
      qval[t] = thing[b * Pp + q0 + t];
      qinv[t] = invn[((size_t)(b * Pp + q0 + t)) * Ll + l];
    }
    float c[4][8];
    #pragma unroll
    for (int m = 0; m < 4; ++m)
      #pragma unroll
      for (int n = 0; n < 8; ++n) c[m][n] = 0.f;

    for (int k0 = 0; k0 < Dd; k0 += TK) {
      __syncthreads();  // also publishes qlab/qinv on first iteration
      {
        const float sA = invA[arow];
        float4 v = *(const float4*)(meta + (((size_t)(b * Pp + p0 + arow)) * Ll + l) * Dd + k0 + aseg * 4);
        A_lds[aseg * 4 + 0][arow] = v.x * sA;
        A_lds[aseg * 4 + 1][arow] = v.y * sA;
        A_lds[aseg * 4 + 2][arow] = v.z * sA;
        A_lds[aseg * 4 + 3][arow] = v.w * sA;
      }
      #pragma unroll
      for (int rr = 0; rr < 2; ++rr) {
        const int row = rr * 64 + arow;
        const float sB = qinv[row];
        float4 v = *(const float4*)(meta + (((size_t)(b * Pp + q0 + row)) * Ll + l) * Dd + k0 + aseg * 4);
        B_lds[aseg * 4 + 0][row] = v.x * sB;
        B_lds[aseg * 4 + 1][row] = v.y * sB;
        B_lds[aseg * 4 + 2][row] = v.z * sB;
        B_lds[aseg * 4 + 3][row] = v.w * sB;
      }
      __syncthreads();
      #pragma unroll
      for (int kk = 0; kk < TK; ++kk) {
        float4 a  = *(const float4*)&A_lds[kk][4 * i];
        float4 b0 = *(const float4*)&B_lds[kk][8 * j];
        float4 b1 = *(const float4*)&B_lds[kk][8 * j + 4];
        const float av[4] = {a.x, a.y, a.z, a.w};
        const float bv[8] = {b0.x, b0.y, b0.z, b0.w, b1.x, b1.y, b1.z, b1.w};
        #pragma unroll
        for (int m = 0; m < 4; ++m)
          #pragma unroll
          for (int n = 0; n < 8; ++n) c[m][n] = fmaf(av[m], bv[n], c[m][n]);
      }
    }
    // epilogue for this 64x128 tile
    #pragma unroll
    for (int n = 0; n < 8; ++n) {
      const int q  = q0 + 8 * j + n;
      const int lq = qlab[8 * j + n];
      const int vq = qval[8 * j + n];
      #pragma unroll
      for (int m = 0; m < 4; ++m) {
        const float z = c[m][n] * INV_TEMP;
        if (vq && lq != labr[m]) partial[m] += __expf(z - M0f);  // negatives
        if (q == qpr[m]) zp_s[4 * i + m] = z;                    // sampled positive (or diag)
        if (q == qir[m]) zl_s[4 * i + m] = z;                    // last negative
      }
    }
  }
  #pragma unroll
  for (int m = 0; m < 4; ++m) atomicAdd(&rowsum[4 * i + m], partial[m]);
  __syncthreads();

  if (t < TM) {  // wave 0, all 64 lanes active
    const int p = p0 + t;
    float contrib = 0.f;
    const int Kb = Kv[b];
    if (valp_s[t]) {
      const float zp = zp_s[t], zl = zl_s[t], rs = rowsum[t];
      const int nc = negc[b * Pp + p];
      const float pad = fmaxf((float)(Kb - 1 - nc), 0.f);
      const float tot = __expf(zp - M0f) + rs + ((nc > 0) ? pad * __expf(zl - M0f) : 0.f);
      contrib = (M0f + logf(tot) - zp) / (float)max(Kb, 1);
    }
    #pragma unroll
    for (int m2 = 32; m2; m2 >>= 1) contrib += __shfl_xor(contrib, m2, 64);
    if (t == 0 && gatev[b]) atomicAdd(out, contrib);
  }
}

}  // namespace

extern "C" void kernel_launch(void* const* d_in, const int* in_sizes, int n_in,
                              void* d_out, int out_size, void* d_ws, size_t ws_size,
                              hipStream_t stream) {
  const float* meta = (const float*)d_in[0];
  const int* thing  = (const int*)d_in[1];
  const int* label  = (const int*)d_in[2];
  float* out = (float*)d_out;

  char* ws = (char*)d_ws;
  size_t off = 0;
  float* invn = (float*)(ws + off); off += (size_t)Bb * Pp * Ll * sizeof(float);   // 196608 B
  int* qpos   = (int*)(ws + off);   off += (size_t)Bb * Ll * Pp * sizeof(int);     // 196608 B
  int* negc   = (int*)(ws + off);   off += (size_t)Bb * Pp * sizeof(int);          // 32768 B
  int* qidx   = (int*)(ws + off);   off += (size_t)Bb * Pp * sizeof(int);          // 32768 B
  int* Kv     = (int*)(ws + off);   off += (size_t)Bb * sizeof(int);
  int* gatev  = (int*)(ws + off);   off += (size_t)Bb * sizeof(int);

  hipMemsetAsync(out, 0, sizeof(float), stream);

  batch_stats_k<<<Bb, 256, 0, stream>>>(thing, Kv, gatev);
  row_stats_k<<<(Bb * Pp + 255) / 256, 256, 0, stream>>>(thing, label, qpos, negc, qidx);
  {
    const int waves = Bb * Pp * Ll;             // 49152 vectors, 1 wave each
    const int blocks = (waves * 64 + 255) / 256;
    norms_k<<<blocks, 256, 0, stream>>>(meta, invn);
  }
  {
    dim3 grid(Pp / TM, Ll, Bb);  // (16, 6, 8) = 768 blocks
    main_loss_k<<<grid, 256, 0, stream>>>(meta, invn, thing, label, qpos, negc, qidx,
                                          Kv, gatev, out);
  }
}

// Round 2
// 197.063 us; speedup vs baseline: 3.6757x; 3.6757x over previous
//
#include <hip/hip_runtime.h>
#include <stdint.h>

namespace {

constexpr int Bb = 8, Ll = 6, Dd = 256, Pp = 1024;
constexpr float SCALE_Y = 14.285714285714286f * 1.4426950408889634f; // (1/0.07)*log2(e)
constexpr float M0y = 21.0f;   // > max |y| = 20.61
constexpr float LN2f = 0.6931471805599453f;

typedef __attribute__((ext_vector_type(8))) short short8;
typedef __attribute__((ext_vector_type(4))) float floatx4;

// ---------------- JAX threefry2x32 (key = (0, 42)), bit-exact ----------------
__device__ __forceinline__ uint32_t rotl32(uint32_t x, int n) {
  return (x << n) | (x >> (32 - n));
}
__device__ __forceinline__ void tf_round(uint32_t& x0, uint32_t& x1, int r) {
  x0 += x1; x1 = rotl32(x1, r); x1 ^= x0;
}
__device__ void threefry2x32(uint32_t x0, uint32_t x1, uint32_t& o0, uint32_t& o1) {
  const uint32_t k0 = 0u, k1 = 42u;
  const uint32_t k2 = k0 ^ k1 ^ 0x1BD11BDAu;
  x0 += k0; x1 += k1;
  tf_round(x0,x1,13); tf_round(x0,x1,15); tf_round(x0,x1,26); tf_round(x0,x1,6);
  x0 += k1; x1 += k2 + 1u;
  tf_round(x0,x1,17); tf_round(x0,x1,29); tf_round(x0,x1,16); tf_round(x0,x1,24);
  x0 += k2; x1 += k0 + 2u;
  tf_round(x0,x1,13); tf_round(x0,x1,15); tf_round(x0,x1,26); tf_round(x0,x1,6);
  x0 += k0; x1 += k1 + 3u;
  tf_round(x0,x1,17); tf_round(x0,x1,29); tf_round(x0,x1,16); tf_round(x0,x1,24);
  x0 += k1; x1 += k2 + 4u;
  tf_round(x0,x1,13); tf_round(x0,x1,15); tf_round(x0,x1,26); tf_round(x0,x1,6);
  x0 += k2; x1 += k0 + 5u;
  o0 = x0; o1 = x1;
}
__device__ float jax_u01(uint32_t idx) {
  const uint32_t HALF = (uint32_t)(Bb * Ll * Pp / 2); // 24576
  uint32_t o0, o1, bits;
  if (idx < HALF) { threefry2x32(idx, idx + HALF, o0, o1); bits = o0; }
  else            { threefry2x32(idx - HALF, idx, o0, o1); bits = o1; }
  return __uint_as_float((bits >> 9) | 0x3f800000u) - 1.0f;
}

__device__ __forceinline__ unsigned short bf16rne(float x) {
  uint32_t u = __float_as_uint(x);
  return (unsigned short)((u + 0x7FFFu + ((u >> 16) & 1u)) >> 16);
}

// ---------------- kernel 1: per-batch K and gate ----------------
__global__ void batch_stats_k(const int* __restrict__ thing, int* __restrict__ Kv,
                              int* __restrict__ gatev) {
  const int b = blockIdx.x, t = threadIdx.x;
  __shared__ int sK[256], sG[256];
  int k = 0;
  for (int p = t; p < Pp; p += 256) k += (thing[b * Pp + p] != 0);
  int g = 0;
  for (int n = t; n < 128; n += 256) {
    int any = 0;
    for (int tt = 0; tt < 8; ++tt) any |= (thing[(b * 128 + n) * 8 + tt] != 0);
    g += any;
  }
  sK[t] = k; sG[t] = g;
  __syncthreads();
  for (int s = 128; s; s >>= 1) {
    if (t < s) { sK[t] += sK[t + s]; sG[t] += sG[t + s]; }
    __syncthreads();
  }
  if (t == 0) { Kv[b] = sK[0]; gatev[b] = (sG[0] >= 2) ? 1 : 0; }
}

// ---------------- kernel 2: wave-parallel row stats + threefry selection ----------------
// one wave per (b,p); ballot/popcount rank machinery
__global__ void row_stats_k(const int* __restrict__ thing, const int* __restrict__ label,
                            int* __restrict__ qpos, int* __restrict__ negc,
                            int* __restrict__ qidx) {
  const int wid = blockIdx.x * 4 + (threadIdx.x >> 6);   // 0 .. B*P-1
  const int lane = threadIdx.x & 63;
  const int b = wid >> 10, p = wid & (Pp - 1);
  const int* lab = label + b * Pp;
  const int* th  = thing + b * Pp;
  const int myLab = lab[p];
  const bool myValid = (th[p] != 0);

  uint32_t posbits = 0;            // bit c: q=c*64+lane is a positive
  int cnt[16];
  int pc = 0, nc = 0, last = -1;
  #pragma unroll
  for (int c = 0; c < 16; ++c) {
    const int q = c * 64 + lane;
    const int lq = lab[q];
    const bool vq = (th[q] != 0);
    const bool same = (lq == myLab);
    const bool pos = myValid && vq && same && (q != p);
    const bool neg = myValid && vq && !same;
    uint64_t bp = __ballot(pos);
    uint64_t bn = __ballot(neg);
    if (pos) posbits |= (1u << c);
    cnt[c] = __popcll(bp);
    pc += cnt[c];
    nc += __popcll(bn);
    if (bn) last = c * 64 + 63 - __clzll(bn);
  }

  int qsel[Ll];
  #pragma unroll
  for (int l = 0; l < Ll; ++l) qsel[l] = p;   // diag fallback
  if (pc > 0) {
    for (int l = 0; l < Ll; ++l) {
      const float u = jax_u01((uint32_t)((b * Ll + l) * Pp + p));
      int r = (int)floorf(u * (float)pc);
      r = min(r, pc - 1);
      int base = 0;
      for (int c = 0; c < 16; ++c) {
        if (r < base + cnt[c]) {
          const bool mine = (posbits >> c) & 1u;
          uint64_t bm = __ballot(mine);
          uint64_t ltmask = (lane == 0) ? 0ull : (~0ull >> (64 - lane));
          int myrank = __popcll(bm & ltmask);
          bool hit = mine && (base + myrank == r);
          uint64_t hb = __ballot(hit);
          qsel[l] = c * 64 + (int)__builtin_ctzll(hb);
          break;
        }
        base += cnt[c];
      }
    }
  }
  if (lane == 0) {
    negc[wid] = nc;
    qidx[wid] = (last < 0) ? 0 : last;
    #pragma unroll
    for (int l = 0; l < Ll; ++l) qpos[(b * Ll + l) * Pp + p] = qsel[l];
  }
}

// ---------------- kernel 3: fused norms + normalize + bf16 convert ----------------
// wn layout: [bl = b*L+l][p][d] bf16, row-contiguous
__global__ void norm_bf16_k(const float* __restrict__ meta, unsigned short* __restrict__ wn) {
  const int wid = (blockIdx.x * 256 + threadIdx.x) >> 6;   // (b*P+p)*L+l
  const int lane = threadIdx.x & 63;
  const float4 v = *(const float4*)(meta + (size_t)wid * Dd + lane * 4);
  float ss = v.x * v.x + v.y * v.y + v.z * v.z + v.w * v.w;
  #pragma unroll
  for (int m = 32; m; m >>= 1) ss += __shfl_xor(ss, m, 64);
  const float inv = 1.0f / fmaxf(sqrtf(ss), 1e-12f);
  const int bp = wid / Ll, l = wid - bp * Ll;
  const int b = bp >> 10, p = bp & (Pp - 1);
  unsigned short* dst = wn + ((size_t)(b * Ll + l) * Pp + p) * Dd + lane * 4;
  ushort4 o;
  o.x = bf16rne(v.x * inv); o.y = bf16rne(v.y * inv);
  o.z = bf16rne(v.z * inv); o.w = bf16rne(v.w * inv);
  *(ushort4*)dst = o;
}

// ---------------- kernel 4: MFMA Gram + masked base-2 LSE epilogue ----------------
// 128x128 tile per block, 4 waves in 2x2, each wave 4x4 frags of 16x16x32 bf16
__global__ __launch_bounds__(256)
void gemm_loss_k(const unsigned short* __restrict__ wn,
                 const int* __restrict__ thing, const int* __restrict__ label,
                 const int* __restrict__ qpos, const int* __restrict__ qidx,
                 float* __restrict__ rowsum_g, float* __restrict__ zp_g,
                 float* __restrict__ zl_g) {
  __shared__ __align__(16) unsigned short As[128 * 64];  // chunk (row,sp) at byte row*128+sp*16
  __shared__ __align__(16) unsigned short Bs[128 * 64];
  __shared__ int labp_s[128], qpos_s[128], qidx_s[128], clab_s[128], cval_s[128];
  __shared__ float rowsum_lds[128];

  const int t = threadIdx.x;
  const int bl = blockIdx.z;
  const int b = bl / Ll;
  const int p0 = blockIdx.x * 128, q0 = blockIdx.y * 128;

  if (t < 128) {
    labp_s[t] = label[b * Pp + p0 + t];
    qpos_s[t] = qpos[bl * Pp + p0 + t];
    qidx_s[t] = qidx[b * Pp + p0 + t];
    clab_s[t] = label[b * Pp + q0 + t];
    cval_s[t] = thing[b * Pp + q0 + t];
    rowsum_lds[t] = 0.f;
  }

  const unsigned short* Wbl = wn + (size_t)bl * Pp * Dd;
  const int lane = t & 63;
  const int w = t >> 6, wr = w >> 1, wc = w & 1;
  const int cq = lane & 15, rq = lane >> 4;

  floatx4 acc[4][4];
  #pragma unroll
  for (int i = 0; i < 4; ++i)
    #pragma unroll
    for (int j = 0; j < 4; ++j) acc[i][j] = (floatx4){0.f, 0.f, 0.f, 0.f};

  for (int k0 = 0; k0 < Dd; k0 += 64) {
    __syncthreads();
    #pragma unroll
    for (int it = 0; it < 4; ++it) {
      const int chunk = it * 256 + t;          // 0..1023: 16B chunks
      const int row = chunk >> 3, sp = chunk & 7;
      const int sl = sp ^ (row & 7);           // XOR swizzle
      const uint4 va = *(const uint4*)(Wbl + (size_t)(p0 + row) * Dd + k0 + sl * 8);
      *(uint4*)((char*)As + chunk * 16) = va;
      const uint4 vb = *(const uint4*)(Wbl + (size_t)(q0 + row) * Dd + k0 + sl * 8);
      *(uint4*)((char*)Bs + chunk * 16) = vb;
    }
    __syncthreads();
    #pragma unroll
    for (int sub = 0; sub < 2; ++sub) {
      short8 af[4], bf[4];
      #pragma unroll
      for (int fi = 0; fi < 4; ++fi) {
        const int row = wr * 64 + fi * 16 + cq;           // A row m = lane&15
        const int sp = (sub * 4 + rq) ^ (row & 7);
        af[fi] = *(const short8*)((const char*)As + row * 128 + sp * 16);
      }
      #pragma unroll
      for (int fj = 0; fj < 4; ++fj) {
        const int row = wc * 64 + fj * 16 + cq;           // B row n = lane&15
        const int sp = (sub * 4 + rq) ^ (row & 7);
        bf[fj] = *(const short8*)((const char*)Bs + row * 128 + sp * 16);
      }
      #pragma unroll
      for (int fi = 0; fi < 4; ++fi)
        #pragma unroll
        for (int fj = 0; fj < 4; ++fj)
          acc[fi][fj] = __builtin_amdgcn_mfma_f32_16x16x32_bf16(af[fi], bf[fj],
                                                                acc[fi][fj], 0, 0, 0);
    }
  }

  // ---------------- epilogue ----------------
  int qcol[4], qlabv[4];
  float qvalf[4];
  #pragma unroll
  for (int fj = 0; fj < 4; ++fj) {
    const int cl = wc * 64 + fj * 16 + cq;
    qcol[fj] = q0 + cl;
    qlabv[fj] = clab_s[cl];
    qvalf[fj] = cval_s[cl] ? 1.f : 0.f;
  }
  #pragma unroll
  for (int fi = 0; fi < 4; ++fi) {
    #pragma unroll
    for (int reg = 0; reg < 4; ++reg) {
      const int rl = wr * 64 + fi * 16 + rq * 4 + reg;    // C row = (lane>>4)*4+reg
      const int rlab = labp_s[rl];
      const int rqp = qpos_s[rl], rqi = qidx_s[rl];
      float rsum = 0.f;
      #pragma unroll
      for (int fj = 0; fj < 4; ++fj) {
        const float y = acc[fi][fj][reg] * SCALE_Y;
        const float negm = (qlabv[fj] != rlab) ? qvalf[fj] : 0.f;
        rsum += negm * exp2f(y - M0y);
        if (qcol[fj] == rqp) zp_g[bl * Pp + p0 + rl] = y;
        if (qcol[fj] == rqi) zl_g[bl * Pp + p0 + rl] = y;
      }
      rsum += __shfl_xor(rsum, 1); rsum += __shfl_xor(rsum, 2);
      rsum += __shfl_xor(rsum, 4); rsum += __shfl_xor(rsum, 8);
      if (cq == 0) atomicAdd(&rowsum_lds[rl], rsum);
    }
  }
  __syncthreads();
  if (t < 128) atomicAdd(&rowsum_g[bl * Pp + p0 + t], rowsum_lds[t]);
}

// ---------------- kernel 5: finalize ----------------
__global__ void finalize_k(const float* __restrict__ rowsum_g, const float* __restrict__ zp_g,
                           const float* __restrict__ zl_g, const int* __restrict__ negc,
                           const int* __restrict__ thing, const int* __restrict__ Kv,
                           const int* __restrict__ gatev, float* __restrict__ out) {
  const int bl = blockIdx.x, b = bl / Ll, t = threadIdx.x;
  const int Kb = Kv[b];
  const float invK = 1.f / (float)max(Kb, 1);
  float acc = 0.f;
  for (int p = t; p < Pp; p += 256) {
    if (thing[b * Pp + p] != 0) {
      const float yp = zp_g[bl * Pp + p], yl = zl_g[bl * Pp + p];
      const float rs = rowsum_g[bl * Pp + p];
      const int nc = negc[b * Pp + p];
      const float pad = fmaxf((float)(Kb - 1 - nc), 0.f);
      const float tot = exp2f(yp - M0y) + rs + ((nc > 0) ? pad * exp2f(yl - M0y) : 0.f);
      acc += LN2f * (M0y + log2f(tot) - yp) * invK;
    }
  }
  __shared__ float sb[256];
  sb[t] = acc;
  __syncthreads();
  for (int s = 128; s; s >>= 1) {
    if (t < s) sb[t] += sb[t + s];
    __syncthreads();
  }
  if (t == 0 && gatev[b]) atomicAdd(out, sb[0]);
}

}  // namespace

extern "C" void kernel_launch(void* const* d_in, const int* in_sizes, int n_in,
                              void* d_out, int out_size, void* d_ws, size_t ws_size,
                              hipStream_t stream) {
  const float* meta = (const float*)d_in[0];
  const int* thing  = (const int*)d_in[1];
  const int* label  = (const int*)d_in[2];
  float* out = (float*)d_out;

  char* ws = (char*)d_ws;
  size_t off = 0;
  unsigned short* wn = (unsigned short*)(ws + off); off += (size_t)Bb * Ll * Pp * Dd * 2; // 25.2 MB
  int* qpos  = (int*)(ws + off); off += (size_t)Bb * Ll * Pp * 4;   // 196608
  int* negc  = (int*)(ws + off); off += (size_t)Bb * Pp * 4;        // 32768
  int* qidx  = (int*)(ws + off); off += (size_t)Bb * Pp * 4;        // 32768
  int* Kv    = (int*)(ws + off); off += 64;
  int* gatev = (int*)(ws + off); off += 64;
  float* rowsum_g = (float*)(ws + off); off += (size_t)Bb * Ll * Pp * 4;
  float* zp_g     = (float*)(ws + off); off += (size_t)Bb * Ll * Pp * 4;
  float* zl_g     = (float*)(ws + off); off += (size_t)Bb * Ll * Pp * 4;

  hipMemsetAsync(out, 0, sizeof(float), stream);
  hipMemsetAsync(rowsum_g, 0, (size_t)Bb * Ll * Pp * 4, stream);

  batch_stats_k<<<Bb, 256, 0, stream>>>(thing, Kv, gatev);
  row_stats_k<<<(Bb * Pp) / 4, 256, 0, stream>>>(thing, label, qpos, negc, qidx);
  norm_bf16_k<<<(Bb * Pp * Ll) / 4, 256, 0, stream>>>(meta, wn);
  {
    dim3 grid(Pp / 128, Pp / 128, Bb * Ll);   // (8, 8, 48)
    gemm_loss_k<<<grid, 256, 0, stream>>>(wn, thing, label, qpos, qidx,
                                          rowsum_g, zp_g, zl_g);
  }
  finalize_k<<<Bb * Ll, 256, 0, stream>>>(rowsum_g, zp_g, zl_g, negc, thing, Kv, gatev, out);
}

// Round 3
// 168.004 us; speedup vs baseline: 4.3114x; 1.1730x over previous
//
#include <hip/hip_runtime.h>
#include <stdint.h>

namespace {

constexpr int Bb = 8, Ll = 6, Dd = 256, Pp = 1024;
constexpr float SCALE_Y = 14.285714285714286f * 1.4426950408889634f; // (1/0.07)*log2(e)
constexpr float M0y = 21.0f;   // > max |y| = 20.61
constexpr float LN2f = 0.6931471805599453f;

typedef __attribute__((ext_vector_type(8))) short short8;
typedef __attribute__((ext_vector_type(4))) float floatx4;

// async global->LDS DMA, 16B per lane; LDS dest = wave-uniform base + lane*16
__device__ __forceinline__ void async16(const void* g, void* l) {
  __builtin_amdgcn_global_load_lds(
      (const __attribute__((address_space(1))) void*)g,
      (__attribute__((address_space(3))) void*)l, 16, 0, 0);
}

// ---------------- JAX threefry2x32 (key = (0, 42)), bit-exact ----------------
__device__ __forceinline__ uint32_t rotl32(uint32_t x, int n) {
  return (x << n) | (x >> (32 - n));
}
__device__ __forceinline__ void tf_round(uint32_t& x0, uint32_t& x1, int r) {
  x0 += x1; x1 = rotl32(x1, r); x1 ^= x0;
}
__device__ void threefry2x32(uint32_t x0, uint32_t x1, uint32_t& o0, uint32_t& o1) {
  const uint32_t k0 = 0u, k1 = 42u;
  const uint32_t k2 = k0 ^ k1 ^ 0x1BD11BDAu;
  x0 += k0; x1 += k1;
  tf_round(x0,x1,13); tf_round(x0,x1,15); tf_round(x0,x1,26); tf_round(x0,x1,6);
  x0 += k1; x1 += k2 + 1u;
  tf_round(x0,x1,17); tf_round(x0,x1,29); tf_round(x0,x1,16); tf_round(x0,x1,24);
  x0 += k2; x1 += k0 + 2u;
  tf_round(x0,x1,13); tf_round(x0,x1,15); tf_round(x0,x1,26); tf_round(x0,x1,6);
  x0 += k0; x1 += k1 + 3u;
  tf_round(x0,x1,17); tf_round(x0,x1,29); tf_round(x0,x1,16); tf_round(x0,x1,24);
  x0 += k1; x1 += k2 + 4u;
  tf_round(x0,x1,13); tf_round(x0,x1,15); tf_round(x0,x1,26); tf_round(x0,x1,6);
  x0 += k2; x1 += k0 + 5u;
  o0 = x0; o1 = x1;
}
__device__ float jax_u01(uint32_t idx) {
  const uint32_t HALF = (uint32_t)(Bb * Ll * Pp / 2); // 24576
  uint32_t o0, o1, bits;
  if (idx < HALF) { threefry2x32(idx, idx + HALF, o0, o1); bits = o0; }
  else            { threefry2x32(idx - HALF, idx, o0, o1); bits = o1; }
  return __uint_as_float((bits >> 9) | 0x3f800000u) - 1.0f;
}

__device__ __forceinline__ unsigned short bf16rne(float x) {
  uint32_t u = __float_as_uint(x);
  return (unsigned short)((u + 0x7FFFu + ((u >> 16) & 1u)) >> 16);
}

// ---------------- fused prep kernel (block-range dispatch) ----------------
// [0, NB_NORM)          : normalize + bf16 convert (1 wave per vector)
// [NB_NORM, +NB_ROW)    : per-row stats + threefry selection (1 wave per row)
// [.., +8)              : per-batch K and gate
// [.., +48)             : zero rowsum_g
// [.., +1)              : zero out
constexpr int NB_NORM = Bb * Pp * Ll / 4;  // 12288
constexpr int NB_ROW  = Bb * Pp / 4;       // 2048

__global__ void prep_k(const float* __restrict__ meta, const int* __restrict__ thing,
                       const int* __restrict__ label, unsigned short* __restrict__ wn,
                       int* __restrict__ qpos, int* __restrict__ negc,
                       int* __restrict__ qidx, int* __restrict__ Kv,
                       int* __restrict__ gatev, float* __restrict__ rowsum_g,
                       float* __restrict__ out) {
  __shared__ int sK[256], sG[256];
  const int bid = blockIdx.x, t = threadIdx.x;

  if (bid < NB_NORM) {
    // ---- normalize + bf16 ----
    const int wid = (bid * 256 + t) >> 6;   // (b*P+p)*L+l
    const int lane = t & 63;
    const float4 v = *(const float4*)(meta + (size_t)wid * Dd + lane * 4);
    float ss = v.x * v.x + v.y * v.y + v.z * v.z + v.w * v.w;
    #pragma unroll
    for (int m = 32; m; m >>= 1) ss += __shfl_xor(ss, m, 64);
    const float inv = 1.0f / fmaxf(sqrtf(ss), 1e-12f);
    const int bp = wid / Ll, l = wid - bp * Ll;
    const int b = bp >> 10, p = bp & (Pp - 1);
    unsigned short* dst = wn + ((size_t)(b * Ll + l) * Pp + p) * Dd + lane * 4;
    ushort4 o;
    o.x = bf16rne(v.x * inv); o.y = bf16rne(v.y * inv);
    o.z = bf16rne(v.z * inv); o.w = bf16rne(v.w * inv);
    *(ushort4*)dst = o;
    return;
  }
  if (bid < NB_NORM + NB_ROW) {
    // ---- row stats: one wave per (b,p) ----
    const int wid = (bid - NB_NORM) * 4 + (t >> 6);
    const int lane = t & 63;
    const int b = wid >> 10, p = wid & (Pp - 1);
    const int* lab = label + b * Pp;
    const int* th  = thing + b * Pp;
    const int myLab = lab[p];
    const bool myValid = (th[p] != 0);

    uint32_t posbits = 0;
    int cnt[16];
    int pc = 0, nc = 0, last = -1;
    #pragma unroll
    for (int c = 0; c < 16; ++c) {
      const int q = c * 64 + lane;
      const int lq = lab[q];
      const bool vq = (th[q] != 0);
      const bool same = (lq == myLab);
      const bool pos = myValid && vq && same && (q != p);
      const bool neg = myValid && vq && !same;
      uint64_t bp2 = __ballot(pos);
      uint64_t bn = __ballot(neg);
      if (pos) posbits |= (1u << c);
      cnt[c] = __popcll(bp2);
      pc += cnt[c];
      nc += __popcll(bn);
      if (bn) last = c * 64 + 63 - __clzll(bn);
    }
    int qsel[Ll];
    #pragma unroll
    for (int l = 0; l < Ll; ++l) qsel[l] = p;
    if (pc > 0) {
      for (int l = 0; l < Ll; ++l) {
        const float u = jax_u01((uint32_t)((b * Ll + l) * Pp + p));
        int r = (int)floorf(u * (float)pc);
        r = min(r, pc - 1);
        int base = 0;
        for (int c = 0; c < 16; ++c) {
          if (r < base + cnt[c]) {
            const bool mine = (posbits >> c) & 1u;
            uint64_t bm = __ballot(mine);
            uint64_t ltmask = (lane == 0) ? 0ull : (~0ull >> (64 - lane));
            int myrank = __popcll(bm & ltmask);
            bool hit = mine && (base + myrank == r);
            uint64_t hb = __ballot(hit);
            qsel[l] = c * 64 + (int)__builtin_ctzll(hb);
            break;
          }
          base += cnt[c];
        }
      }
    }
    if (lane == 0) {
      negc[wid] = nc;
      qidx[wid] = (last < 0) ? 0 : last;
      #pragma unroll
      for (int l = 0; l < Ll; ++l) qpos[(b * Ll + l) * Pp + p] = qsel[l];
    }
    return;
  }
  if (bid < NB_NORM + NB_ROW + Bb) {
    // ---- batch stats ----
    const int b = bid - (NB_NORM + NB_ROW);
    int k = 0;
    for (int p = t; p < Pp; p += 256) k += (thing[b * Pp + p] != 0);
    int g = 0;
    if (t < 128) {
      int any = 0;
      for (int tt = 0; tt < 8; ++tt) any |= (thing[(b * 128 + t) * 8 + tt] != 0);
      g = any;
    }
    sK[t] = k; sG[t] = g;
    __syncthreads();
    for (int s = 128; s; s >>= 1) {
      if (t < s) { sK[t] += sK[t + s]; sG[t] += sG[t + s]; }
      __syncthreads();
    }
    if (t == 0) { Kv[b] = sK[0]; gatev[b] = (sG[0] >= 2) ? 1 : 0; }
    return;
  }
  if (bid < NB_NORM + NB_ROW + Bb + 48) {
    // ---- zero rowsum_g (48*1024 floats = 48 blocks * 256 thr * float4) ----
    const int idx = (bid - (NB_NORM + NB_ROW + Bb)) * 256 + t;
    *(float4*)(rowsum_g + idx * 4) = (float4){0.f, 0.f, 0.f, 0.f};
    return;
  }
  if (t == 0) out[0] = 0.f;
}

// ---------------- MFMA Gram + masked base-2 LSE epilogue ----------------
// 128x128 tile per block, 4 waves in 2x2, each wave 4x4 frags of 16x16x32 bf16
// staging via global_load_lds width=16
__global__ __launch_bounds__(256)
void gemm_loss_k(const unsigned short* __restrict__ wn,
                 const int* __restrict__ thing, const int* __restrict__ label,
                 const int* __restrict__ qpos, const int* __restrict__ qidx,
                 float* __restrict__ rowsum_g, float* __restrict__ zp_g,
                 float* __restrict__ zl_g) {
  __shared__ __align__(16) unsigned short As[128 * 64];  // physical chunk c at byte c*16
  __shared__ __align__(16) unsigned short Bs[128 * 64];
  __shared__ int labp_s[128], qpos_s[128], qidx_s[128], clab_s[128], cval_s[128];
  __shared__ float rowsum_lds[128];

  const int t = threadIdx.x;
  const int bl = blockIdx.z;
  const int b = bl / Ll;
  const int p0 = blockIdx.x * 128, q0 = blockIdx.y * 128;

  if (t < 128) {
    labp_s[t] = label[b * Pp + p0 + t];
    qpos_s[t] = qpos[bl * Pp + p0 + t];
    qidx_s[t] = qidx[b * Pp + p0 + t];
    clab_s[t] = label[b * Pp + q0 + t];
    cval_s[t] = thing[b * Pp + q0 + t];
    rowsum_lds[t] = 0.f;
  }

  const unsigned short* Wbl = wn + (size_t)bl * Pp * Dd;
  const int lane = t & 63;
  const int w = t >> 6, wr = w >> 1, wc = w & 1;
  const int cq = lane & 15, rq = lane >> 4;
  const int wbase16 = (t & ~63) * 16;  // wave-uniform lds byte base per 64-lane group

  floatx4 acc[4][4];
  #pragma unroll
  for (int i = 0; i < 4; ++i)
    #pragma unroll
    for (int j = 0; j < 4; ++j) acc[i][j] = (floatx4){0.f, 0.f, 0.f, 0.f};

  for (int k0 = 0; k0 < Dd; k0 += 64) {
    __syncthreads();   // LDS safe to overwrite (also orders the t<128 preload, 1st iter)
    #pragma unroll
    for (int it = 0; it < 4; ++it) {
      const int c = it * 256 + t;            // 16B chunk id: row = c>>3, physical sp = c&7
      const int row = c >> 3, sp = c & 7;
      const int sl = sp ^ (row & 7);         // XOR swizzle: logical k-slot stored here
      const char* lbase = (const char*)0 + it * 4096 + wbase16;  // byte offset
      async16(Wbl + (size_t)(p0 + row) * Dd + k0 + sl * 8, (char*)As + it * 4096 + wbase16);
      async16(Wbl + (size_t)(q0 + row) * Dd + k0 + sl * 8, (char*)Bs + it * 4096 + wbase16);
      (void)lbase;
    }
    __syncthreads();   // drains vmcnt -> tiles visible
    #pragma unroll
    for (int sub = 0; sub < 2; ++sub) {
      short8 af[4], bf[4];
      #pragma unroll
      for (int fi = 0; fi < 4; ++fi) {
        const int row = wr * 64 + fi * 16 + cq;           // A row m = lane&15
        const int sp = (sub * 4 + rq) ^ (row & 7);
        af[fi] = *(const short8*)((const char*)As + row * 128 + sp * 16);
      }
      #pragma unroll
      for (int fj = 0; fj < 4; ++fj) {
        const int row = wc * 64 + fj * 16 + cq;           // B row n = lane&15
        const int sp = (sub * 4 + rq) ^ (row & 7);
        bf[fj] = *(const short8*)((const char*)Bs + row * 128 + sp * 16);
      }
      #pragma unroll
      for (int fi = 0; fi < 4; ++fi)
        #pragma unroll
        for (int fj = 0; fj < 4; ++fj)
          acc[fi][fj] = __builtin_amdgcn_mfma_f32_16x16x32_bf16(af[fi], bf[fj],
                                                                acc[fi][fj], 0, 0, 0);
    }
  }

  // ---------------- epilogue ----------------
  int qcol[4], qlabv[4];
  float qvalf[4];
  #pragma unroll
  for (int fj = 0; fj < 4; ++fj) {
    const int cl = wc * 64 + fj * 16 + cq;
    qcol[fj] = q0 + cl;
    qlabv[fj] = clab_s[cl];
    qvalf[fj] = cval_s[cl] ? 1.f : 0.f;
  }
  #pragma unroll
  for (int fi = 0; fi < 4; ++fi) {
    #pragma unroll
    for (int reg = 0; reg < 4; ++reg) {
      const int rl = wr * 64 + fi * 16 + rq * 4 + reg;    // C row = (lane>>4)*4+reg
      const int rlab = labp_s[rl];
      const int rqp = qpos_s[rl], rqi = qidx_s[rl];
      float rsum = 0.f;
      #pragma unroll
      for (int fj = 0; fj < 4; ++fj) {
        const float y = acc[fi][fj][reg] * SCALE_Y;
        const float negm = (qlabv[fj] != rlab) ? qvalf[fj] : 0.f;
        rsum += negm * exp2f(y - M0y);
        if (qcol[fj] == rqp) zp_g[bl * Pp + p0 + rl] = y;
        if (qcol[fj] == rqi) zl_g[bl * Pp + p0 + rl] = y;
      }
      rsum += __shfl_xor(rsum, 1); rsum += __shfl_xor(rsum, 2);
      rsum += __shfl_xor(rsum, 4); rsum += __shfl_xor(rsum, 8);
      if (cq == 0) atomicAdd(&rowsum_lds[rl], rsum);
    }
  }
  __syncthreads();
  if (t < 128) atomicAdd(&rowsum_g[bl * Pp + p0 + t], rowsum_lds[t]);
}

// ---------------- finalize ----------------
__global__ void finalize_k(const float* __restrict__ rowsum_g, const float* __restrict__ zp_g,
                           const float* __restrict__ zl_g, const int* __restrict__ negc,
                           const int* __restrict__ thing, const int* __restrict__ Kv,
                           const int* __restrict__ gatev, float* __restrict__ out) {
  const int bl = blockIdx.x, b = bl / Ll, t = threadIdx.x;
  const int Kb = Kv[b];
  const float invK = 1.f / (float)max(Kb, 1);
  float acc = 0.f;
  for (int p = t; p < Pp; p += 256) {
    if (thing[b * Pp + p] != 0) {
      const float yp = zp_g[bl * Pp + p], yl = zl_g[bl * Pp + p];
      const float rs = rowsum_g[bl * Pp + p];
      const int nc = negc[b * Pp + p];
      const float pad = fmaxf((float)(Kb - 1 - nc), 0.f);
      const float tot = exp2f(yp - M0y) + rs + ((nc > 0) ? pad * exp2f(yl - M0y) : 0.f);
      acc += LN2f * (M0y + log2f(tot) - yp) * invK;
    }
  }
  __shared__ float sb[256];
  sb[t] = acc;
  __syncthreads();
  for (int s = 128; s; s >>= 1) {
    if (t < s) sb[t] += sb[t + s];
    __syncthreads();
  }
  if (t == 0 && gatev[b]) atomicAdd(out, sb[0]);
}

}  // namespace

extern "C" void kernel_launch(void* const* d_in, const int* in_sizes, int n_in,
                              void* d_out, int out_size, void* d_ws, size_t ws_size,
                              hipStream_t stream) {
  const float* meta = (const float*)d_in[0];
  const int* thing  = (const int*)d_in[1];
  const int* label  = (const int*)d_in[2];
  float* out = (float*)d_out;

  char* ws = (char*)d_ws;
  size_t off = 0;
  unsigned short* wn = (unsigned short*)(ws + off); off += (size_t)Bb * Ll * Pp * Dd * 2; // 25.2 MB
  int* qpos  = (int*)(ws + off); off += (size_t)Bb * Ll * Pp * 4;
  int* negc  = (int*)(ws + off); off += (size_t)Bb * Pp * 4;
  int* qidx  = (int*)(ws + off); off += (size_t)Bb * Pp * 4;
  int* Kv    = (int*)(ws + off); off += 64;
  int* gatev = (int*)(ws + off); off += 64;
  float* rowsum_g = (float*)(ws + off); off += (size_t)Bb * Ll * Pp * 4;
  float* zp_g     = (float*)(ws + off); off += (size_t)Bb * Ll * Pp * 4;
  float* zl_g     = (float*)(ws + off); off += (size_t)Bb * Ll * Pp * 4;

  const int nb_prep = NB_NORM + NB_ROW + Bb + 48 + 1;  // 14345
  prep_k<<<nb_prep, 256, 0, stream>>>(meta, thing, label, wn, qpos, negc, qidx,
                                      Kv, gatev, rowsum_g, out);
  {
    dim3 grid(Pp / 128, Pp / 128, Bb * Ll);   // (8, 8, 48)
    gemm_loss_k<<<grid, 256, 0, stream>>>(wn, thing, label, qpos, qidx,
                                          rowsum_g, zp_g, zl_g);
  }
  finalize_k<<<Bb * Ll, 256, 0, stream>>>(rowsum_g, zp_g, zl_g, negc, thing, Kv, gatev, out);
}